// Round 3
// baseline (449.345 us; speedup 1.0000x reference)
//
#include <hip/hip_runtime.h>
#include <math.h>

// GMM per-pixel sampling: out = mu[k] + exp(log_std[k]) * eps,
// k = #(cdf < u), cdf = cumsum(softmax(pi_logits)) over K=10 (innermost).
// Shapes [B,F,T,K] = [16,256,1024,10]; rows are 40 B.
//
// R3: ONE pixel per thread, ZERO local arrays. R1/R2 kept float l[20]/e[10]
// arrays and the compiler demoted them to scratch (VGPR_Count=24 with 30+
// live floats!) -> every thread ping-ponged its logits through private
// memory, serializing on vmcnt waits: both pipes <25% busy at 79% occupancy,
// and time was insensitive to global-load count (R1 166us -> R2 158us).
// Here everything is named scalars: row loaded as 5 x float2 (8B-aligned,
// 40p % 8 == 0), softmax fully straight-line, mu/log_std fetched by 4 B
// gather (touches the same HBM lines a row read would).
//
// Arithmetic order is kept IDENTICAL to the twice-passing R1/R2 chain:
// sequential fmaxf, e_j = expf(l_j - m), sequential S accumulation,
// cdf += e_j / S with per-element IEEE divide, strict cdf < u, clip to K-1.

#define KMIX 10

__global__ __launch_bounds__(256) void gmm_sample_kernel(
    const float* __restrict__ mu,
    const float* __restrict__ log_std,
    const float* __restrict__ pi_logits,
    const float* __restrict__ u_cat,
    const float* __restrict__ eps,
    float* __restrict__ out,
    int n)
{
    int p = blockIdx.x * blockDim.x + threadIdx.x;
    if (p >= n) return;

    size_t base = (size_t)p * KMIX;

    // Row = 40 B = 5 x float2, always 8 B aligned. All loads issue up front.
    const float2* r2 = reinterpret_cast<const float2*>(pi_logits + base);
    float2 v0 = r2[0];
    float2 v1 = r2[1];
    float2 v2 = r2[2];
    float2 v3 = r2[3];
    float2 v4 = r2[4];
    float u  = u_cat[p];
    float ev = eps[p];

    float l0 = v0.x, l1 = v0.y, l2 = v1.x, l3 = v1.y, l4 = v2.x,
          l5 = v2.y, l6 = v3.x, l7 = v3.y, l8 = v4.x, l9 = v4.y;

    // max — sequential chain, same order as reference loop j=1..9
    float m = l0;
    m = fmaxf(m, l1); m = fmaxf(m, l2); m = fmaxf(m, l3);
    m = fmaxf(m, l4); m = fmaxf(m, l5); m = fmaxf(m, l6);
    m = fmaxf(m, l7); m = fmaxf(m, l8); m = fmaxf(m, l9);

    float e0 = expf(l0 - m), e1 = expf(l1 - m), e2 = expf(l2 - m),
          e3 = expf(l3 - m), e4 = expf(l4 - m), e5 = expf(l5 - m),
          e6 = expf(l6 - m), e7 = expf(l7 - m), e8 = expf(l8 - m),
          e9 = expf(l9 - m);

    // S — sequential accumulation, same order as reference
    float S = e0;
    S += e1; S += e2; S += e3; S += e4;
    S += e5; S += e6; S += e7; S += e8; S += e9;

    // cdf = cumsum(e_j / S), per-element IEEE divide; k = #(cdf < u) strict
    float cdf = 0.f;
    int k = 0;
    cdf += e0 / S; k += (cdf < u) ? 1 : 0;
    cdf += e1 / S; k += (cdf < u) ? 1 : 0;
    cdf += e2 / S; k += (cdf < u) ? 1 : 0;
    cdf += e3 / S; k += (cdf < u) ? 1 : 0;
    cdf += e4 / S; k += (cdf < u) ? 1 : 0;
    cdf += e5 / S; k += (cdf < u) ? 1 : 0;
    cdf += e6 / S; k += (cdf < u) ? 1 : 0;
    cdf += e7 / S; k += (cdf < u) ? 1 : 0;
    cdf += e8 / S; k += (cdf < u) ? 1 : 0;
    cdf += e9 / S; k += (cdf < u) ? 1 : 0;
    if (k > KMIX - 1) k = KMIX - 1;   // jnp.clip(k, 0, K-1)

    // Gather the selected component (4 B each; same HBM lines as a row read)
    size_t idx = base + (size_t)k;
    float mk = mu[idx];
    float sk = log_std[idx];

    out[p] = mk + expf(sk) * ev;
}

extern "C" void kernel_launch(void* const* d_in, const int* in_sizes, int n_in,
                              void* d_out, int out_size, void* d_ws, size_t ws_size,
                              hipStream_t stream) {
    const float* mu        = (const float*)d_in[0];
    const float* log_std   = (const float*)d_in[1];
    const float* pi_logits = (const float*)d_in[2];
    const float* u_cat     = (const float*)d_in[3];
    const float* eps       = (const float*)d_in[4];
    float* out = (float*)d_out;

    int N = in_sizes[3];          // B*F*T = 4,194,304
    int block = 256;
    int grid = (N + block - 1) / block;
    gmm_sample_kernel<<<grid, block, 0, stream>>>(mu, log_std, pi_logits,
                                                  u_cat, eps, out, N);
}